// Round 1
// baseline (442.322 us; speedup 1.0000x reference)
//
#include <hip/hip_runtime.h>

#define NNODE 1000
#define D 64
#define K_TOP 20
#define NROWS 32000   // B*N = 32*1000

// ---------------- inverse norms (f64) ----------------
__global__ void norms_kernel(const float* __restrict__ e0, const float* __restrict__ e1,
                             const float* __restrict__ e2, double* __restrict__ inv_nrm) {
    int g = blockIdx.y;
    const float* e = (g == 0) ? e0 : ((g == 1) ? e1 : e2);
    int j = blockIdx.x * 256 + threadIdx.x;
    if (j < NNODE) {
        double s = 0.0;
        #pragma unroll
        for (int k = 0; k < D; ++k) { double v = (double)e[j * D + k]; s += v * v; }
        inv_nrm[g * NNODE + j] = 1.0 / sqrt(s);
    }
}

// ---------------- top-20 of cosine row (f64, tie -> smaller index) ----------------
__global__ void topk_kernel(const float* __restrict__ emb, const double* __restrict__ inv_nrm,
                            int* __restrict__ idx_out, float* __restrict__ idxf_out) {
    __shared__ float srow[D];
    __shared__ double scos[NNODE];
    __shared__ double sval[256];
    __shared__ int sidx[256];
    int i = blockIdx.x;
    int tid = threadIdx.x;
    if (tid < D) srow[tid] = emb[i * D + tid];
    __syncthreads();
    double inv_i = inv_nrm[i];
    for (int j = tid; j < NNODE; j += 256) {
        const float* ej = emb + j * D;
        double acc = 0.0;
        #pragma unroll
        for (int k = 0; k < D; ++k) acc += (double)ej[k] * (double)srow[k];
        scos[j] = acc * inv_i * inv_nrm[j];
    }
    __syncthreads();
    for (int r = 0; r < K_TOP; ++r) {
        double best = -1.0e300; int bi = 0x7fffffff;
        for (int j = tid; j < NNODE; j += 256) {
            double v = scos[j];
            if (v > best || (v == best && j < bi)) { best = v; bi = j; }
        }
        sval[tid] = best; sidx[tid] = bi;
        __syncthreads();
        for (int s = 128; s > 0; s >>= 1) {
            if (tid < s) {
                double v = sval[tid + s]; int vi = sidx[tid + s];
                if (v > sval[tid] || (v == sval[tid] && vi < sidx[tid])) { sval[tid] = v; sidx[tid] = vi; }
            }
            __syncthreads();
        }
        if (tid == 0) {
            int w = sidx[0];
            idx_out[i * K_TOP + r] = w;
            if (idxf_out) idxf_out[i * K_TOP + r] = (float)w;
            scos[w] = -1.0e301;  // remove winner
        }
        __syncthreads();
    }
}

// ---------------- row GEMM: out[row][c] = bias[c] + sum_k X[row][xoff+k]*W[k][c] ----------------
template <int K>
__global__ void rowgemm_kernel(const float* __restrict__ X, int ldx, int xoff,
                               const float* __restrict__ W, const float* __restrict__ bias,
                               float* __restrict__ out) {
    __shared__ float Ws[K * D];
    __shared__ float xs[4][K];
    int tid = threadIdx.x;
    for (int e = tid; e < K * D; e += 256) Ws[e] = W[e];
    int base_row = blockIdx.x * 4;
    for (int e = tid; e < 4 * K; e += 256) {
        int r = e / K, k = e % K;
        xs[r][k] = X[(size_t)(base_row + r) * ldx + xoff + k];
    }
    __syncthreads();
    int lr = tid >> 6, c = tid & 63;
    float acc = bias[c];
    #pragma unroll
    for (int k = 0; k < K; ++k) acc = fmaf(xs[lr][k], Ws[k * D + c], acc);
    out[(size_t)(base_row + lr) * D + c] = acc;
}

// ---------------- GCN gather-mean-relu (+optional x output), t = y*emb ----------------
__global__ void gcn_kernel(const float* __restrict__ h, const int* __restrict__ idx,
                           const float* __restrict__ emb, float* __restrict__ t_out,
                           float* __restrict__ x_out) {
    __shared__ int nbrs[4][K_TOP];
    int tid = threadIdx.x;
    int lr = tid >> 6, c = tid & 63;
    int row = blockIdx.x * 4 + lr;
    int b = row / NNODE, i = row % NNODE;
    if (c < K_TOP) nbrs[lr][c] = idx[i * K_TOP + c];
    __syncthreads();
    const float* hb = h + (size_t)b * NNODE * D;
    float s = 0.f;
    #pragma unroll
    for (int t = 0; t < K_TOP; ++t) s += hb[(size_t)nbrs[lr][t] * D + c];
    float y = fmaxf(s * (1.0f / 20.0f), 0.f);
    if (x_out) x_out[(size_t)row * D + c] = y;
    t_out[(size_t)row * D + c] = y * emb[i * D + c];
}

// ---------------- BN stats: per-block partial sums (f64, deterministic) ----------------
__global__ void bn_partial_kernel(const float* __restrict__ t, double* __restrict__ psum,
                                  double* __restrict__ psq) {
    __shared__ double sh[256], sh2[256];
    int tid = threadIdx.x;
    const float* base = t + (size_t)blockIdx.x * 125 * D;
    double s = 0.0, ss = 0.0;
    for (int e = tid; e < 125 * D; e += 256) {
        double v = (double)base[e];
        s += v; ss += v * v;
    }
    sh[tid] = s; sh2[tid] = ss;
    __syncthreads();
    if (tid < 128) { sh[tid] += sh[tid + 128]; sh2[tid] += sh2[tid + 128]; }
    __syncthreads();
    if (tid < 64) {
        psum[(size_t)blockIdx.x * D + tid] = sh[tid] + sh[tid + 64];
        psq[(size_t)blockIdx.x * D + tid] = sh2[tid] + sh2[tid + 64];
    }
}

__global__ void bn_final_kernel(const double* __restrict__ psum, const double* __restrict__ psq,
                                const float* __restrict__ g, const float* __restrict__ beta,
                                float* __restrict__ ss_out) {
    int c = threadIdx.x;
    if (c < D) {
        double s = 0.0, sq = 0.0;
        for (int b2 = 0; b2 < 256; ++b2) { s += psum[b2 * D + c]; sq += psq[b2 * D + c]; }
        const double n = (double)NROWS;
        double mu = s / n;
        double var = sq / n - mu * mu;
        double inv = 1.0 / sqrt(var + 1e-5);
        double sc = (double)g[c] * inv;
        ss_out[c] = (float)sc;
        ss_out[D + c] = (float)((double)beta[c] - mu * sc);
    }
}

// ---------------- BN-apply + 64x64 GEMM ----------------
__global__ void bn_gemm64_kernel(const float* __restrict__ t, const float* __restrict__ ss,
                                 const float* __restrict__ W, const float* __restrict__ bias,
                                 float* __restrict__ out) {
    __shared__ float Ws[D * D];
    __shared__ float v[4][D];
    int tid = threadIdx.x;
    for (int e = tid; e < D * D; e += 256) Ws[e] = W[e];
    int lr = tid >> 6, c = tid & 63;
    int row = blockIdx.x * 4 + lr;
    float x = t[(size_t)row * D + c];
    v[lr][c] = fmaxf(fmaf(x, ss[c], ss[D + c]), 0.f);
    __syncthreads();
    float acc = bias[c];
    #pragma unroll
    for (int k = 0; k < D; ++k) acc = fmaf(v[lr][k], Ws[k * D + c], acc);
    out[(size_t)row * D + c] = acc;
}

// ---------------- BN-apply + 64->1 projection ----------------
__global__ void phy_out_kernel(const float* __restrict__ t, const float* __restrict__ ss,
                               const float* __restrict__ Wp, const float* __restrict__ bp,
                               float* __restrict__ out) {
    int tid = threadIdx.x;
    int lr = tid >> 6, c = tid & 63;
    int row = blockIdx.x * 4 + lr;
    float x = t[(size_t)row * D + c];
    float bnv = fmaxf(fmaf(x, ss[c], ss[D + c]), 0.f);
    float p = bnv * Wp[c];
    #pragma unroll
    for (int s = 32; s > 0; s >>= 1) p += __shfl_down(p, s, 64);
    if (c == 0) out[row] = p + bp[0];
}

// ---------------- BN-apply + 64->3 projection ----------------
__global__ void net_out_kernel(const float* __restrict__ t, const float* __restrict__ ss,
                               const float* __restrict__ Wn, const float* __restrict__ bn_,
                               float* __restrict__ out) {
    int tid = threadIdx.x;
    int lr = tid >> 6, c = tid & 63;
    int row = blockIdx.x * 4 + lr;
    float x = t[(size_t)row * D + c];
    float bnv = fmaxf(fmaf(x, ss[c], ss[D + c]), 0.f);
    float p0 = bnv * Wn[c * 3 + 0];
    float p1 = bnv * Wn[c * 3 + 1];
    float p2 = bnv * Wn[c * 3 + 2];
    #pragma unroll
    for (int s = 32; s > 0; s >>= 1) {
        p0 += __shfl_down(p0, s, 64);
        p1 += __shfl_down(p1, s, 64);
        p2 += __shfl_down(p2, s, 64);
    }
    if (c == 0) {
        out[(size_t)row * 3 + 0] = p0 + bn_[0];
        out[(size_t)row * 3 + 1] = p1 + bn_[1];
        out[(size_t)row * 3 + 2] = p2 + bn_[2];
    }
}

extern "C" void kernel_launch(void* const* d_in, const int* in_sizes, int n_in,
                              void* d_out, int out_size, void* d_ws, size_t ws_size,
                              hipStream_t stream) {
    const float* data    = (const float*)d_in[0];
    // d_in[1..3] = edge_index arrays: unused by the reference
    const float* mul_emb = (const float*)d_in[4];
    const float* phy_emb = (const float*)d_in[5];
    const float* net_emb = (const float*)d_in[6];
    const float* W_share = (const float*)d_in[7];
    const float* b_share = (const float*)d_in[8];
    const float* W_phy   = (const float*)d_in[9];
    const float* b_phy   = (const float*)d_in[10];
    const float* W_net   = (const float*)d_in[11];
    const float* b_net   = (const float*)d_in[12];
    const float* g_mul   = (const float*)d_in[13];
    const float* be_mul  = (const float*)d_in[14];
    const float* g_phy   = (const float*)d_in[15];
    const float* be_phy  = (const float*)d_in[16];
    const float* g_net   = (const float*)d_in[17];
    const float* be_net  = (const float*)d_in[18];
    const float* W_out   = (const float*)d_in[19];
    const float* b_out   = (const float*)d_in[20];
    const float* W_pout  = (const float*)d_in[21];
    const float* b_pout  = (const float*)d_in[22];
    const float* W_nout  = (const float*)d_in[23];
    const float* b_nout  = (const float*)d_in[24];

    float* outf = (float*)d_out;
    float* out_phy  = outf;            // 32000
    float* out_net  = outf + 32000;    // 96000
    float* out_idx  = outf + 128000;   // 20000 (idx_mul as floats)
    float* out_xnet = outf + 148000;   // 2048000
    float* out_xphy = outf + 2196000;  // 2048000

    char* ws = (char*)d_ws;
    size_t off = 0;
    auto alloc = [&](size_t bytes) -> void* {
        void* p = (void*)(ws + off);
        off += bytes;
        off = (off + 255) & ~(size_t)255;
        return p;
    };
    int* idxM = (int*)alloc(20000 * 4);
    int* idxP = (int*)alloc(20000 * 4);
    int* idxN = (int*)alloc(20000 * 4);
    double* inv_nrm = (double*)alloc(3000 * 8);
    double* psum = (double*)alloc(256 * 64 * 8);
    double* psq  = (double*)alloc(256 * 64 * 8);
    float* ssM = (float*)alloc(128 * 4);
    float* ssP = (float*)alloc(128 * 4);
    float* ssN = (float*)alloc(128 * 4);
    float* A  = (float*)alloc((size_t)NROWS * D * 4);  // h_share -> h_phy
    float* Bb = (float*)alloc((size_t)NROWS * D * 4);  // t_mul   -> h_net
    float* C  = (float*)alloc((size_t)NROWS * D * 4);  // out_mid -> t_phy
    float* Dd = (float*)alloc((size_t)NROWS * D * 4);  // t_net

    // 1. graphs (f64 cosine, exact ranking)
    norms_kernel<<<dim3(4, 3), 256, 0, stream>>>(mul_emb, phy_emb, net_emb, inv_nrm);
    topk_kernel<<<1000, 256, 0, stream>>>(mul_emb, inv_nrm, idxM, out_idx);
    topk_kernel<<<1000, 256, 0, stream>>>(phy_emb, inv_nrm + 1000, idxP, (float*)nullptr);
    topk_kernel<<<1000, 256, 0, stream>>>(net_emb, inv_nrm + 2000, idxN, (float*)nullptr);

    // 2. mul path
    rowgemm_kernel<60><<<8000, 256, 0, stream>>>(data, 60, 0, W_share, b_share, A);
    gcn_kernel<<<8000, 256, 0, stream>>>(A, idxM, mul_emb, Bb, (float*)nullptr);
    bn_partial_kernel<<<256, 256, 0, stream>>>(Bb, psum, psq);
    bn_final_kernel<<<1, 64, 0, stream>>>(psum, psq, g_mul, be_mul, ssM);
    bn_gemm64_kernel<<<8000, 256, 0, stream>>>(Bb, ssM, W_out, b_out, C);

    // 3. phy / net heads
    rowgemm_kernel<16><<<8000, 256, 0, stream>>>(C, 64, 0, W_phy, b_phy, A);
    rowgemm_kernel<48><<<8000, 256, 0, stream>>>(C, 64, 16, W_net, b_net, Bb);
    gcn_kernel<<<8000, 256, 0, stream>>>(A, idxP, phy_emb, C, out_xphy);
    gcn_kernel<<<8000, 256, 0, stream>>>(Bb, idxN, net_emb, Dd, out_xnet);

    bn_partial_kernel<<<256, 256, 0, stream>>>(C, psum, psq);
    bn_final_kernel<<<1, 64, 0, stream>>>(psum, psq, g_phy, be_phy, ssP);
    phy_out_kernel<<<8000, 256, 0, stream>>>(C, ssP, W_pout, b_pout, out_phy);

    bn_partial_kernel<<<256, 256, 0, stream>>>(Dd, psum, psq);
    bn_final_kernel<<<1, 64, 0, stream>>>(psum, psq, g_net, be_net, ssN);
    net_out_kernel<<<8000, 256, 0, stream>>>(Dd, ssN, W_nout, b_nout, out_net);
}